// Round 8
// baseline (7983.390 us; speedup 1.0000x reference)
//
#include <hip/hip_runtime.h>
#include <stdint.h>

// Problem constants
#define T_LEN 1024
#define D_IN  128
#define HID   256
#define NCLS  10
#define NGRP  8      // batch groups (16 batches each)
#define NCB   8      // column-blocks per group (32 units each)
#define BB    16     // batches per group (== MFMA M)

// Workspace layout (bytes)
#define WT_BYTES   (8*8*16*64*8*2)          // 1,048,576: pre-tiled B-fragments
#define BIAS_OFF   WT_BYTES                 // 1024 fp32 = 4 KB
#define FLAGS_OFF  (BIAS_OFF + 4096)        // 8g*8j*8w u32 = 2 KB (pad to 4 KB)
#define HBUF_OFF   (FLAGS_OFF + 4096)       // 2 slots * 8g * 16b * 256u bf16 = 128 KB

typedef __attribute__((ext_vector_type(8))) short s16x8;
typedef __attribute__((ext_vector_type(4))) float f32x4;
typedef __attribute__((ext_vector_type(4))) unsigned short u16x4;
typedef unsigned long long u64;

__device__ __forceinline__ unsigned short f2bf(float f) {
    union { float f; uint32_t u; } v; v.f = f;
    return (unsigned short)((v.u + 0x7FFFu + ((v.u >> 16) & 1u)) >> 16);
}
__device__ __forceinline__ float bf2f(unsigned short s) {
    union { uint32_t u; float f; } v; v.u = ((uint32_t)s) << 16;
    return v.f;
}
__device__ __forceinline__ float fsig(float x) {
    return __builtin_amdgcn_rcpf(1.0f + __builtin_amdgcn_exp2f(-1.44269504f * x));
}
__device__ __forceinline__ float ftanh(float x) {
    return 2.0f * __builtin_amdgcn_rcpf(1.0f + __builtin_amdgcn_exp2f(-2.88539008f * x)) - 1.0f;
}

// Pre-tile weights: frag idx = ((j*8 + w)*16 + bt)*64 + lane, 8 bf16 each.
// Column order (wave-local elementwise): n = lane&15 -> ur = n>>2, gate = n&3,
// unit = 32j + 4w + ur (weight column). ko = (lane>>4)*8 + e.
// bt 0-3: Wx_hi k=bt*32+ko | bt 4-7: Wx_lo residual | bt 8-15: Wh k=(bt-8)*32+ko
__global__ void prep_kernel(const float* __restrict__ Wgx, const float* __restrict__ Wix,
                            const float* __restrict__ Wfx, const float* __restrict__ Wox,
                            const float* __restrict__ Wgh, const float* __restrict__ Wih,
                            const float* __restrict__ Wfh, const float* __restrict__ Woh,
                            const float* __restrict__ bg,  const float* __restrict__ bi,
                            const float* __restrict__ bf_, const float* __restrict__ bo,
                            const float* __restrict__ bp,
                            unsigned short* __restrict__ WT, float* __restrict__ bias_ws,
                            unsigned int* __restrict__ flags, u64* __restrict__ hbuf,
                            float* __restrict__ out) {
    int idx = blockIdx.x * 256 + threadIdx.x;   // 65536 threads
    int l  = idx & 63;
    int bt = (idx >> 6) & 15;
    int w  = (idx >> 10) & 7;
    int j  = (idx >> 13) & 7;
    int n  = l & 15;
    int unit = 32 * j + 4 * w + (n >> 2);
    int gate = n & 3;
    const float* wx = (gate == 0) ? Wgx : (gate == 1) ? Wix : (gate == 2) ? Wfx : Wox;
    const float* wh = (gate == 0) ? Wgh : (gate == 1) ? Wih : (gate == 2) ? Wfh : Woh;
    unsigned short o8[8];
#pragma unroll
    for (int e = 0; e < 8; ++e) {
        int ko = (l >> 4) * 8 + e;
        unsigned short r;
        if (bt < 8) {
            int k = (bt & 3) * 32 + ko;
            float v = wx[k * HID + unit];
            unsigned short hi = f2bf(v);
            r = (bt < 4) ? hi : f2bf(v - bf2f(hi));
        } else {
            r = f2bf(wh[((bt - 8) * 32 + ko) * HID + unit]);
        }
        o8[e] = r;
    }
    u16x4* dst = (u16x4*)(WT + (size_t)idx * 8);
    dst[0] = *(u16x4*)&o8[0];
    dst[1] = *(u16x4*)&o8[4];

    if (idx < 1024) {                     // bias by global column (gate*256 + unit)
        int g2 = idx >> 8, u2 = idx & 255;
        const float* bb = (g2 == 0) ? bg : (g2 == 1) ? bi : (g2 == 2) ? bf_ : bo;
        bias_ws[idx] = bb[u2];
    } else if (idx >= 1024 && idx < 1536) {        // zero flags (512)
        flags[idx - 1024] = 0;
    } else if (idx >= 2048 && idx < 2048 + 16384) { // zero hbuf (128 KB)
        hbuf[idx - 2048] = 0;
    } else if (idx >= 20480 && idx < 20480 + BB * NGRP * NCLS) {
        int i2 = idx - 20480;
        out[i2] = bp[i2 % NCLS];          // init out with bias
    }
}

// 64 blocks x 512 threads, zero barriers in the main loop. Block (g=bid&7, j=bid>>3).
// Wave w owns units [32j+4w, 32j+4w+4) x all 16 batches of group g.
__global__ __launch_bounds__(512, 1) void lstm_kernel(
        const float* __restrict__ x, const unsigned short* __restrict__ WT,
        const float* __restrict__ bias_ws, const float* __restrict__ Wph,
        unsigned int* __restrict__ flags, u64* __restrict__ hbuf,
        float* __restrict__ out) {
    __shared__ float wlds[8][16][16];          // per-wave 4x4 gate transpose
    __shared__ unsigned short ldsH[BB][32];    // final h for projection

    const int tid  = threadIdx.x;
    const int lane = tid & 63;
    const int w    = tid >> 6;
    const int g    = blockIdx.x & 7;           // same-XCD grouping heuristic (perf only)
    const int j    = blockIdx.x >> 3;
    const int mrow = lane & 15;                // MFMA A-row (frag) / C-col (acc)
    const int kq   = lane >> 4;
    const int ur   = mrow >> 2;                // unit-rel
    const int gg   = mrow & 3;                 // gate (column role)
    const int bb   = 4 * kq + gg;              // elementwise batch

    // weight slice -> 64 AGPRs/lane, pinned resident all 1024 steps
    s16x8 Bf[16];
    {
        const unsigned short* wp = WT + ((size_t)((j * 8 + w) * 16) * 64 + lane) * 8;
#pragma unroll
        for (int bt = 0; bt < 16; ++bt) Bf[bt] = *(const s16x8*)(wp + (size_t)bt * 512);
    }
#pragma unroll
    for (int bt = 0; bt < 16; ++bt) asm volatile("" : "+a"(Bf[bt]));

    const float bias_r = bias_ws[gg * 256 + 32 * j + 4 * w + ur];

    // per-lane x fragment source; prefetch t=0 (32 f32)
    const float* xlane = x + ((size_t)(g * 16 + mrow) * T_LEN) * D_IN + kq * 8;
    float4 xr[8];
#pragma unroll
    for (int c = 0; c < 4; ++c) {
        xr[2 * c]     = *(const float4*)(xlane + c * 32);
        xr[2 * c + 1] = *(const float4*)(xlane + c * 32 + 4);
    }

    unsigned int* myflag = flags + g * 64 + j * 8 + w;
    const unsigned int* pollf = flags + g * 64 + lane;     // lane l polls producer (j'=l>>3, w'=l&7)
    u64* hb_w = hbuf + g * 1024 + (size_t)bb * 64 + (8 * j + w);   // publish addr (lanes ur==0)
    const u64* hb_r = hbuf + g * 1024 + (size_t)mrow * 64;         // consumer row base

    float c_reg = 0.0f;
    unsigned int hmine = 0;

    for (int t = 0; t < T_LEN; ++t) {
        // convert x(t) f32 -> hi/lo bf16 frags (VALU; hazard-padded inside MFMA block)
        s16x8 xhi[4], xlo[4];
#pragma unroll
        for (int c = 0; c < 4; ++c) {
            union { s16x8 v; unsigned short s[8]; } H, L;
#pragma unroll
            for (int e = 0; e < 8; ++e) {
                float f = (e < 4) ? ((const float*)&xr[2 * c])[e]
                                  : ((const float*)&xr[2 * c + 1])[e - 4];
                unsigned short hi = f2bf(f);
                H.s[e] = hi;
                L.s[e] = f2bf(f - bf2f(hi));
            }
            xhi[c] = H.v; xlo[c] = L.v;
        }
        // prefetch x(t+1)
        {
            const float* xn = xlane + (size_t)((t + 1 < T_LEN) ? (t + 1) : t) * D_IN;
#pragma unroll
            for (int c = 0; c < 4; ++c) {
                xr[2 * c]     = *(const float4*)(xn + c * 32);
                xr[2 * c + 1] = *(const float4*)(xn + c * 32 + 4);
            }
        }
        // poll all 64 producer flags of the group (one per lane)
        {
            unsigned int f;
            do {
                f = __hip_atomic_load(pollf, __ATOMIC_RELAXED, __HIP_MEMORY_SCOPE_AGENT);
            } while (f < (unsigned)t);
        }
        asm volatile("" ::: "memory");          // keep h loads below the poll

        // h[t-1] fragments: one dwordx4 per k-slice, agent/system-coherent (LLC),
        // loaded straight into the MFMA A-operand tuple (no VALU assembly).
        const u64* hbL = hb_r + (size_t)((t + 1) & 1) * 8192;
        s16x8 hf[8];
#pragma unroll
        for (int q = 0; q < 8; ++q) {
            const u64* p = hbL + q * 8 + kq * 2;
            asm volatile("global_load_dwordx4 %0, %1, off sc0 sc1"
                         : "=v"(hf[q]) : "v"(p) : "memory");
        }

        // x-part MFMAs run under the h-load latency. Single asm block:
        // s_nop prologue guarantees VALU-write -> MFMA-read wait states.
        f32x4 accX = { bias_r, bias_r, bias_r, bias_r };
        asm volatile(
            "s_nop 7\n\t"
            "v_mfma_f32_16x16x32_bf16 %0, %1, %9,  %0\n\t"
            "v_mfma_f32_16x16x32_bf16 %0, %5, %9,  %0\n\t"
            "v_mfma_f32_16x16x32_bf16 %0, %1, %13, %0\n\t"
            "v_mfma_f32_16x16x32_bf16 %0, %2, %10, %0\n\t"
            "v_mfma_f32_16x16x32_bf16 %0, %6, %10, %0\n\t"
            "v_mfma_f32_16x16x32_bf16 %0, %2, %14, %0\n\t"
            "v_mfma_f32_16x16x32_bf16 %0, %3, %11, %0\n\t"
            "v_mfma_f32_16x16x32_bf16 %0, %7, %11, %0\n\t"
            "v_mfma_f32_16x16x32_bf16 %0, %3, %15, %0\n\t"
            "v_mfma_f32_16x16x32_bf16 %0, %4, %12, %0\n\t"
            "v_mfma_f32_16x16x32_bf16 %0, %8, %12, %0\n\t"
            "v_mfma_f32_16x16x32_bf16 %0, %4, %16, %0"
            : "+v"(accX)
            : "v"(xhi[0]), "v"(xhi[1]), "v"(xhi[2]), "v"(xhi[3]),
              "v"(xlo[0]), "v"(xlo[1]), "v"(xlo[2]), "v"(xlo[3]),
              "a"(Bf[0]), "a"(Bf[1]), "a"(Bf[2]), "a"(Bf[3]),
              "a"(Bf[4]), "a"(Bf[5]), "a"(Bf[6]), "a"(Bf[7]));

        // wait h-load data (volatile-asm order pins this between the blocks)
        asm volatile("s_waitcnt vmcnt(0)" ::: "memory");

        // h-part MFMAs, 2 chains; s_nop epilogue covers MFMA -> VALU-read hazard
        f32x4 accA = { 0, 0, 0, 0 }, accB = { 0, 0, 0, 0 };
        asm volatile(
            "s_nop 3\n\t"
            "v_mfma_f32_16x16x32_bf16 %0, %2, %10, %0\n\t"
            "v_mfma_f32_16x16x32_bf16 %1, %3, %11, %1\n\t"
            "v_mfma_f32_16x16x32_bf16 %0, %4, %12, %0\n\t"
            "v_mfma_f32_16x16x32_bf16 %1, %5, %13, %1\n\t"
            "v_mfma_f32_16x16x32_bf16 %0, %6, %14, %0\n\t"
            "v_mfma_f32_16x16x32_bf16 %1, %7, %15, %1\n\t"
            "v_mfma_f32_16x16x32_bf16 %0, %8, %16, %0\n\t"
            "v_mfma_f32_16x16x32_bf16 %1, %9, %17, %1\n\t"
            "s_nop 7\n\t"
            "s_nop 7\n\t"
            "s_nop 7"
            : "+v"(accA), "+v"(accB)
            : "v"(hf[0]), "v"(hf[1]), "v"(hf[2]), "v"(hf[3]),
              "v"(hf[4]), "v"(hf[5]), "v"(hf[6]), "v"(hf[7]),
              "a"(Bf[8]),  "a"(Bf[9]),  "a"(Bf[10]), "a"(Bf[11]),
              "a"(Bf[12]), "a"(Bf[13]), "a"(Bf[14]), "a"(Bf[15]));

        f32x4 acc = accX + accA + accB;

        // per-wave 4x4 transpose via LDS (same-wave LDS pipe is in-order;
        // fence blocks compiler reordering)
#pragma unroll
        for (int r = 0; r < 4; ++r) wlds[w][4 * kq + r][mrow] = acc[r];
        asm volatile("" ::: "memory");
        f32x4 gv = *(const f32x4*)&wlds[w][bb][ur * 4];   // [pg,pi,pf,po] of (bb, unit ur)

        // elementwise cell update (lane owns (batch bb, unit 32j+4w+ur))
        c_reg = ftanh(gv[0]) * fsig(gv[1]) + c_reg * fsig(gv[2]);
        float h = ftanh(c_reg) * fsig(gv[3]);
        hmine = f2bf(h);

        // pack units 0..3 into u64 (shfl over ur), publish, drain, flag
        unsigned int v01 = hmine | (((unsigned int)__shfl_down((int)hmine, 4)) << 16);
        unsigned int v23 = (unsigned int)__shfl_down((int)v01, 8);
        if (ur == 0) {
            u64 val = (u64)v01 | ((u64)v23 << 32);
            __hip_atomic_store(hb_w + (size_t)(t & 1) * 8192, val,
                               __ATOMIC_RELAXED, __HIP_MEMORY_SCOPE_AGENT);
        }
        asm volatile("s_waitcnt vmcnt(0)" ::: "memory");   // data at LLC before flag
        if (lane == 0)
            __hip_atomic_store(myflag, (unsigned int)(t + 1),
                               __ATOMIC_RELAXED, __HIP_MEMORY_SCOPE_AGENT);
    }

    // final projection
    ldsH[bb][4 * w + ur] = (unsigned short)hmine;
    __syncthreads();
    if (tid < BB * NCLS) {
        int b = tid / NCLS, cls = tid - b * NCLS;
        float s = 0.0f;
#pragma unroll
        for (int u = 0; u < 32; ++u)
            s += bf2f(ldsH[b][u]) * Wph[(32 * j + u) * NCLS + cls];
        atomicAdd(&out[(g * BB + b) * NCLS + cls], s);
    }
}

extern "C" void kernel_launch(void* const* d_in, const int* in_sizes, int n_in,
                              void* d_out, int out_size, void* d_ws, size_t ws_size,
                              hipStream_t stream) {
    const float* x   = (const float*)d_in[0];
    const float* Wgx = (const float*)d_in[1];
    const float* Wgh = (const float*)d_in[2];
    const float* bg  = (const float*)d_in[3];
    const float* Wix = (const float*)d_in[4];
    const float* Wih = (const float*)d_in[5];
    const float* bi  = (const float*)d_in[6];
    const float* Wfx = (const float*)d_in[7];
    const float* Wfh = (const float*)d_in[8];
    const float* bf_ = (const float*)d_in[9];
    const float* Wox = (const float*)d_in[10];
    const float* Woh = (const float*)d_in[11];
    const float* bo  = (const float*)d_in[12];
    const float* Wph = (const float*)d_in[13];
    const float* bp  = (const float*)d_in[14];

    unsigned short* WT  = (unsigned short*)d_ws;
    float* bias_ws      = (float*)((char*)d_ws + BIAS_OFF);
    unsigned int* flags = (unsigned int*)((char*)d_ws + FLAGS_OFF);
    u64* hbuf           = (u64*)((char*)d_ws + HBUF_OFF);

    prep_kernel<<<256, 256, 0, stream>>>(
        Wgx, Wix, Wfx, Wox, Wgh, Wih, Wfh, Woh, bg, bi, bf_, bo, bp,
        WT, bias_ws, flags, hbuf, (float*)d_out);
    lstm_kernel<<<NGRP * NCB, 512, 0, stream>>>(
        x, WT, bias_ws, Wph, flags, hbuf, (float*)d_out);
}